// Round 3
// baseline (270.611 us; speedup 1.0000x reference)
//
#include <hip/hip_runtime.h>

// y[i] = (x[i]*W0 >= x[i]*W1) ? -1.0f : +1.0f
// (argmax over [x*W0, x*W1] with first-max tie-break, then 2*idx-1)
// Memory-bound elementwise op.
//
// v2: nontemporal loads/stores (302 MB footprint > 256 MB LLC; bypass
//     L2/MALL insertion).  247.3 -> 243.0 us.
// v3: 8x float4 per thread, grid-stride batch. One load per thread gave
//     TLP-only latency hiding (~4.9 TB/s); 8 NT loads in flight/thread
//     targets the ~6.3 TB/s bidirectional stream ceiling.
//     Predicate kept bit-identical (absmax = 0).

typedef float floatx4 __attribute__((ext_vector_type(4)));

#define UNROLL 8

__global__ __launch_bounds__(256) void metaconv_sign4(
    const floatx4* __restrict__ x4,
    const float* __restrict__ W,
    floatx4* __restrict__ out4,
    int n4)
{
    const int stride = gridDim.x * blockDim.x;       // total threads
    const int base   = blockIdx.x * blockDim.x + threadIdx.x;
    const float w0 = W[0];
    const float w1 = W[1];

    floatx4 v[UNROLL];
    int idx[UNROLL];

    // Issue all loads first: 8 x 16B nontemporal loads in flight.
#pragma unroll
    for (int k = 0; k < UNROLL; ++k) {
        idx[k] = base + k * stride;
        if (idx[k] < n4) v[k] = __builtin_nontemporal_load(&x4[idx[k]]);
    }

#pragma unroll
    for (int k = 0; k < UNROLL; ++k) {
        if (idx[k] < n4) {
            floatx4 r;
            r.x = (v[k].x * w0 >= v[k].x * w1) ? -1.0f : 1.0f;
            r.y = (v[k].y * w0 >= v[k].y * w1) ? -1.0f : 1.0f;
            r.z = (v[k].z * w0 >= v[k].z * w1) ? -1.0f : 1.0f;
            r.w = (v[k].w * w0 >= v[k].w * w1) ? -1.0f : 1.0f;
            __builtin_nontemporal_store(r, &out4[idx[k]]);
        }
    }
}

__global__ void metaconv_sign_tail(
    const float* __restrict__ x,
    const float* __restrict__ W,
    float* __restrict__ out,
    int start, int n)
{
    int i = start + blockIdx.x * blockDim.x + threadIdx.x;
    float w0 = W[0];
    float w1 = W[1];
    if (i < n) {
        float v = x[i];
        out[i] = (v * w0 >= v * w1) ? -1.0f : 1.0f;
    }
}

extern "C" void kernel_launch(void* const* d_in, const int* in_sizes, int n_in,
                              void* d_out, int out_size, void* d_ws, size_t ws_size,
                              hipStream_t stream)
{
    const float* x = (const float*)d_in[0];
    const float* W = (const float*)d_in[1];
    float* out = (float*)d_out;

    int n = in_sizes[0];          // 2048*2048*3*3 = 37,748,736
    int n4 = n >> 2;              // float4 count (n divisible by 4 here)
    int rem = n & 3;

    if (n4 > 0) {
        const int block = 256;
        int threads_needed = (n4 + UNROLL - 1) / UNROLL;   // 1,179,648
        int grid = (threads_needed + block - 1) / block;   // 4,608 blocks (18/CU)
        metaconv_sign4<<<grid, block, 0, stream>>>(
            (const floatx4*)x, W, (floatx4*)out, n4);
    }
    if (rem > 0) {
        metaconv_sign_tail<<<1, 64, 0, stream>>>(x, W, out, n4 << 2, n);
    }
}

// Round 4
// 248.858 us; speedup vs baseline: 1.0874x; 1.0874x over previous
//
#include <hip/hip_runtime.h>

// y[i] = (x[i]*W0 >= x[i]*W1) ? -1.0f : +1.0f
// (argmax over [x*W0, x*W1] with first-max tie-break, then 2*idx-1)
// Memory-bound elementwise op.
//
// v2: nontemporal float4 loads/stores (302 MB > 256 MB LLC). 247->243 us.
// v3: batch-8 upfront loads REGRESSED (243->271): MLP already TLP-saturated
//     (8192 waves x 1KB ~ 8MB in flight > 5.7MB BW*latency product); the
//     18MB-strided 8-load batch scattered DRAM locality. Reverted.
// v4: v2 body in a sequential grid-stride loop, 2048 blocks (8 WG/CU).
//     36,864 one-shot WGs cost ~10-15us of CP dispatch ramp for a
//     ~20-instruction kernel; grid-stride removes it. unroll(1) keeps
//     loads sequential in time (avoids v3's scatter). Predicate bit-identical.

typedef float floatx4 __attribute__((ext_vector_type(4)));

__global__ __launch_bounds__(256) void metaconv_sign4(
    const floatx4* __restrict__ x4,
    const float* __restrict__ W,
    floatx4* __restrict__ out4,
    int n4)
{
    const int stride = gridDim.x * blockDim.x;   // 524,288 threads
    const float w0 = W[0];
    const float w1 = W[1];

#pragma unroll 1
    for (int i = blockIdx.x * blockDim.x + threadIdx.x; i < n4; i += stride) {
        floatx4 v = __builtin_nontemporal_load(&x4[i]);
        floatx4 r;
        r.x = (v.x * w0 >= v.x * w1) ? -1.0f : 1.0f;
        r.y = (v.y * w0 >= v.y * w1) ? -1.0f : 1.0f;
        r.z = (v.z * w0 >= v.z * w1) ? -1.0f : 1.0f;
        r.w = (v.w * w0 >= v.w * w1) ? -1.0f : 1.0f;
        __builtin_nontemporal_store(r, &out4[i]);
    }
}

__global__ void metaconv_sign_tail(
    const float* __restrict__ x,
    const float* __restrict__ W,
    float* __restrict__ out,
    int start, int n)
{
    int i = start + blockIdx.x * blockDim.x + threadIdx.x;
    float w0 = W[0];
    float w1 = W[1];
    if (i < n) {
        float v = x[i];
        out[i] = (v * w0 >= v * w1) ? -1.0f : 1.0f;
    }
}

extern "C" void kernel_launch(void* const* d_in, const int* in_sizes, int n_in,
                              void* d_out, int out_size, void* d_ws, size_t ws_size,
                              hipStream_t stream)
{
    const float* x = (const float*)d_in[0];
    const float* W = (const float*)d_in[1];
    float* out = (float*)d_out;

    int n = in_sizes[0];          // 2048*2048*3*3 = 37,748,736
    int n4 = n >> 2;              // float4 count (n divisible by 4 here)
    int rem = n & 3;

    if (n4 > 0) {
        const int block = 256;
        // 2048 blocks = 8 WG/CU on 256 CUs; n4 = 524,288 * 18 exactly,
        // so every thread runs exactly 18 iterations (no tail divergence).
        int grid = 2048;
        int max_grid = (n4 + block - 1) / block;
        if (grid > max_grid) grid = max_grid;
        metaconv_sign4<<<grid, block, 0, stream>>>(
            (const floatx4*)x, W, (floatx4*)out, n4);
    }
    if (rem > 0) {
        metaconv_sign_tail<<<1, 64, 0, stream>>>(x, W, out, n4 << 2, n);
    }
}

// Round 5
// 243.319 us; speedup vs baseline: 1.1122x; 1.0228x over previous
//
#include <hip/hip_runtime.h>

// y[i] = (x[i]*W0 >= x[i]*W1) ? -1.0f : +1.0f
// (argmax over [x*W0, x*W1] with first-max tie-break, then 2*idx-1)
// Memory-bound elementwise op: one nontemporal float4 per thread.
//
// Ladder (measured):
//   v1 cached float4, one-shot grid:            247.3 us
//   v2 +nontemporal load/store:                 243.0 us  <-- BEST
//   v3 batch-8 upfront NT loads:                270.6 us  (REGRESSED:
//       TLP already saturates BW*latency ~5.7MB in-flight; 18MB-strided
//       batch scattered DRAM locality)
//   v4 grid-stride 2048 blocks x18 iters:       248.9 us  (REGRESSED:
//       8MB-stride loop walk + loop overhead > dispatch ramp cost)
// Conclusion: v2 is the local optimum AND within ~10% of the realistic
// bidirectional-stream ceiling (302 MB; pure-write fills hit 6.6 TB/s,
// mixed R+W ~85-90% of that). Reverting to v2 verbatim.

typedef float floatx4 __attribute__((ext_vector_type(4)));

__global__ __launch_bounds__(256) void metaconv_sign4(
    const floatx4* __restrict__ x4,
    const float* __restrict__ W,
    floatx4* __restrict__ out4,
    int n4)
{
    int i = blockIdx.x * blockDim.x + threadIdx.x;
    // Wave-uniform scalar loads; L1/L2-resident after first touch.
    float w0 = W[0];
    float w1 = W[1];
    if (i < n4) {
        floatx4 v = __builtin_nontemporal_load(&x4[i]);
        floatx4 r;
        r.x = (v.x * w0 >= v.x * w1) ? -1.0f : 1.0f;
        r.y = (v.y * w0 >= v.y * w1) ? -1.0f : 1.0f;
        r.z = (v.z * w0 >= v.z * w1) ? -1.0f : 1.0f;
        r.w = (v.w * w0 >= v.w * w1) ? -1.0f : 1.0f;
        __builtin_nontemporal_store(r, &out4[i]);
    }
}

__global__ void metaconv_sign_tail(
    const float* __restrict__ x,
    const float* __restrict__ W,
    float* __restrict__ out,
    int start, int n)
{
    int i = start + blockIdx.x * blockDim.x + threadIdx.x;
    float w0 = W[0];
    float w1 = W[1];
    if (i < n) {
        float v = x[i];
        out[i] = (v * w0 >= v * w1) ? -1.0f : 1.0f;
    }
}

extern "C" void kernel_launch(void* const* d_in, const int* in_sizes, int n_in,
                              void* d_out, int out_size, void* d_ws, size_t ws_size,
                              hipStream_t stream)
{
    const float* x = (const float*)d_in[0];
    const float* W = (const float*)d_in[1];
    float* out = (float*)d_out;

    int n = in_sizes[0];          // 2048*2048*3*3 = 37,748,736
    int n4 = n >> 2;              // float4 count (n divisible by 4 here)
    int rem = n & 3;

    if (n4 > 0) {
        const int block = 256;
        int grid = (n4 + block - 1) / block;
        metaconv_sign4<<<grid, block, 0, stream>>>(
            (const floatx4*)x, W, (floatx4*)out, n4);
    }
    if (rem > 0) {
        metaconv_sign_tail<<<1, 64, 0, stream>>>(x, W, out, n4 << 2, n);
    }
}